// Round 7
// baseline (195.238 us; speedup 1.0000x reference)
//
#include <hip/hip_runtime.h>
#include <math.h>

#define BB 8
#define DD 128
#define HWD 65536    // 256*256
#define NBLK 2048    // 524288 px / 256 px per block

__device__ __forceinline__ float warp_red_sum(float v) {
#pragma unroll
    for (int off = 32; off > 0; off >>= 1) v += __shfl_down(v, off, 64);
    return v;
}

// ws layout (floats): [0]=flag(int), [8..15]=loss_sum, [16..23]=cnt_sum
// flag: 0=uint8, 1=int32, 2=float32, 3=int64
__global__ void detect_and_init(const uint4* __restrict__ mb, float* __restrict__ ws) {
    __shared__ int any_gt1, any_m4, any_m84;
    if (threadIdx.x == 0) { any_gt1 = 0; any_m4 = 0; any_m84 = 0; }
    if (threadIdx.x >= 8 && threadIdx.x < 24) ws[threadIdx.x] = 0.f;
    __syncthreads();
    int lg = 0, l4 = 0, l84 = 0;
#pragma unroll
    for (int it = 0; it < 16; ++it) {
        const int i = it * 256 + threadIdx.x;   // 4096 uint4 = 64 KB window
        uint4 w = mb[i];
        unsigned int anyw = w.x | w.y | w.z | w.w;
        if (anyw & 0xFEFEFEFEu) lg = 1;            // byte > 1 -> float bits
        if (anyw & 0xFFFFFF00u) l4 = 1;            // nonzero at off%4!=0 -> uint8
        if ((w.y | w.w) & 0xFFu) l84 = 1;          // nonzero at off%8==4 -> int32
    }
    if (lg)  atomicOr(&any_gt1, 1);
    if (l4)  atomicOr(&any_m4, 1);
    if (l84) atomicOr(&any_m84, 1);
    __syncthreads();
    if (threadIdx.x == 0) {
        int f;
        if (any_gt1)      f = 2;   // float32
        else if (any_m4)  f = 0;   // uint8/bool
        else if (any_m84) f = 1;   // int32
        else if (any_gt1 | any_m4 | any_m84) f = 3;   // int64
        else              f = 0;   // all-zero window: uint8 is bounds-safe default
        ((int*)ws)[0] = f;
    }
}

// 512 threads = 8 waves. Block covers 256 pixels x 128 channels.
// Wave w owns channels [16w,16w+16); lane L owns pixels 4L..4L+3 (float4 loads).
// Nothing held across phases: pass 2 re-loads (block-local 256 KB -> L2/L3-hot).
// launch_bounds(512,2): 128-VGPR budget -> no spill (R5's 64-cap spilled 365 MB),
// still 4 waves/SIMD occupancy at <=128 VGPR.
__global__ __launch_bounds__(512, 2)
void pixel_dino_main(const float* __restrict__ s_feats,
                     const float* __restrict__ t_feats,
                     const float* __restrict__ center,
                     const void*  __restrict__ mask,
                     const float* __restrict__ orig_x,
                     const float* __restrict__ ws_ro,
                     float* __restrict__ ws) {
    const float TAU_S_INV = 10.0f, TAU_T_INV = 25.0f, EPSN = 1e-12f;
    const int tid  = threadIdx.x;
    const int lane = tid & 63;
    const int wave = tid >> 6;                       // 0..7
    const int b    = blockIdx.x >> 8;                // 256 blocks per image
    const int px   = ((blockIdx.x & 255) << 8) + (lane << 2);
    const float* sp = s_feats + (size_t)b * (DD * HWD) + px;
    const float* tp = t_feats + (size_t)b * (DD * HWD) + px;
    const int d0 = wave * 16;

    __shared__ float red[3][8][256];
    __shared__ float tot[3][256];

    // ---- pass 1: norm partial sums (stream, accumulate, hold nothing) ----
    float ssx = 0.f, ssy = 0.f, ssz = 0.f, ssw = 0.f;
    float ttx = 0.f, tty = 0.f, ttz = 0.f, ttw = 0.f;
#pragma unroll
    for (int k = 0; k < 16; ++k) {
        const float4 s4 = *reinterpret_cast<const float4*>(sp + (size_t)(d0 + k) * HWD);
        const float4 t4 = *reinterpret_cast<const float4*>(tp + (size_t)(d0 + k) * HWD);
        const float c = center[d0 + k];              // wave-uniform -> SGPR
        const float tx = t4.x - c, ty = t4.y - c, tz = t4.z - c, tw = t4.w - c;
        ssx += s4.x * s4.x; ssy += s4.y * s4.y; ssz += s4.z * s4.z; ssw += s4.w * s4.w;
        ttx += tx * tx;     tty += ty * ty;     ttz += tz * tz;     ttw += tw * tw;
    }
    {
        float4* r0 = reinterpret_cast<float4*>(&red[0][wave][lane << 2]);
        float4* r1 = reinterpret_cast<float4*>(&red[1][wave][lane << 2]);
        *r0 = make_float4(ssx, ssy, ssz, ssw);
        *r1 = make_float4(ttx, tty, ttz, ttw);
    }
    __syncthreads();
    {   // 2 quantities x 256 pixels = 512 items, one per thread
        const int q = tid >> 8, p = tid & 255;
        float v = 0.f;
#pragma unroll
        for (int w = 0; w < 8; ++w) v += red[q][w][p];
        tot[q][p] = v;
    }
    __syncthreads();

    const float4 ssT = *reinterpret_cast<const float4*>(&tot[0][lane << 2]);
    const float4 ttT = *reinterpret_cast<const float4*>(&tot[1][lane << 2]);
    const float rsx = TAU_S_INV / fmaxf(sqrtf(ssT.x), EPSN);
    const float rsy = TAU_S_INV / fmaxf(sqrtf(ssT.y), EPSN);
    const float rsz = TAU_S_INV / fmaxf(sqrtf(ssT.z), EPSN);
    const float rsw = TAU_S_INV / fmaxf(sqrtf(ssT.w), EPSN);
    const float rtx = TAU_T_INV / fmaxf(sqrtf(ttT.x), EPSN);
    const float rty = TAU_T_INV / fmaxf(sqrtf(ttT.y), EPSN);
    const float rtz = TAU_T_INV / fmaxf(sqrtf(ttT.z), EPSN);
    const float rtw = TAU_T_INV / fmaxf(sqrtf(ttT.w), EPSN);

    // ---- pass 2: exp sums; re-load (L2/L3-hot). No max-subtraction:
    // |s_hat|/tau_s <= 10, |t_hat|/tau_t <= 25 -> exp fp32-safe. ----
    float ebx = 0.f, eby = 0.f, ebz = 0.f, ebw = 0.f;
    float eax = 0.f, eay = 0.f, eaz = 0.f, eaw = 0.f;
    float cx = 0.f, cy = 0.f, cz = 0.f, cw = 0.f;    // eab
#pragma unroll
    for (int k = 0; k < 16; ++k) {
        const float4 s4 = *reinterpret_cast<const float4*>(sp + (size_t)(d0 + k) * HWD);
        const float4 t4 = *reinterpret_cast<const float4*>(tp + (size_t)(d0 + k) * HWD);
        const float c = center[d0 + k];
        const float bvx = s4.x * rsx, bvy = s4.y * rsy, bvz = s4.z * rsz, bvw = s4.w * rsw;
        const float avx = (t4.x - c) * rtx, avy = (t4.y - c) * rty;
        const float avz = (t4.z - c) * rtz, avw = (t4.w - c) * rtw;
        const float e2x = __expf(avx), e2y = __expf(avy);
        const float e2z = __expf(avz), e2w = __expf(avw);
        ebx += __expf(bvx); eby += __expf(bvy); ebz += __expf(bvz); ebw += __expf(bvw);
        eax += e2x; eay += e2y; eaz += e2z; eaw += e2w;
        cx += e2x * bvx; cy += e2y * bvy; cz += e2z * bvz; cw += e2w * bvw;
    }
    {
        float4* r0 = reinterpret_cast<float4*>(&red[0][wave][lane << 2]);
        float4* r1 = reinterpret_cast<float4*>(&red[1][wave][lane << 2]);
        float4* r2 = reinterpret_cast<float4*>(&red[2][wave][lane << 2]);
        *r0 = make_float4(ebx, eby, ebz, ebw);
        *r1 = make_float4(eax, eay, eaz, eaw);
        *r2 = make_float4(cx, cy, cz, cw);
    }
    __syncthreads();
    {   // 3 quantities x 256 pixels = 768 items
        {
            const int q = tid >> 8, p = tid & 255;
            float v = 0.f;
#pragma unroll
            for (int w = 0; w < 8; ++w) v += red[q][w][p];
            tot[q][p] = v;
        }
        const int idx2 = tid + 512;
        if (idx2 < 768) {
            const int q = idx2 >> 8, p = idx2 & 255;
            float v = 0.f;
#pragma unroll
            for (int w = 0; w < 8; ++w) v += red[q][w][p];
            tot[q][p] = v;
        }
    }
    __syncthreads();

    if (wave == 0) {
        const float4 ebT  = *reinterpret_cast<const float4*>(&tot[0][lane << 2]);
        const float4 eaT  = *reinterpret_cast<const float4*>(&tot[1][lane << 2]);
        const float4 eabT = *reinterpret_cast<const float4*>(&tot[2][lane << 2]);
        const float l0 = __logf(ebT.x) - eabT.x / eaT.x;
        const float l1 = __logf(ebT.y) - eabT.y / eaT.y;
        const float l2 = __logf(ebT.z) - eabT.z / eaT.z;
        const float l3 = __logf(ebT.w) - eabT.w / eaT.w;

        const int gidx = b * HWD + px;
        const int flag = ((const int*)ws_ro)[0];
        bool m0, m1, m2, m3;
        if (flag == 0) {
            const unsigned int m = *reinterpret_cast<const unsigned int*>(
                (const unsigned char*)mask + gidx);
            m0 = (m & 0x000000FFu) != 0; m1 = (m & 0x0000FF00u) != 0;
            m2 = (m & 0x00FF0000u) != 0; m3 = (m & 0xFF000000u) != 0;
        } else if (flag == 1) {
            const int4 m = *reinterpret_cast<const int4*>((const int*)mask + gidx);
            m0 = m.x != 0; m1 = m.y != 0; m2 = m.z != 0; m3 = m.w != 0;
        } else if (flag == 2) {
            const float4 m = *reinterpret_cast<const float4*>((const float*)mask + gidx);
            m0 = m.x != 0.f; m1 = m.y != 0.f; m2 = m.z != 0.f; m3 = m.w != 0.f;
        } else {
            const longlong2 ma = *reinterpret_cast<const longlong2*>((const long long*)mask + gidx);
            const longlong2 mb2 = *reinterpret_cast<const longlong2*>((const long long*)mask + gidx + 2);
            m0 = ma.x != 0; m1 = ma.y != 0; m2 = mb2.x != 0; m3 = mb2.y != 0;
        }
        const float4 ox = *reinterpret_cast<const float4*>(orig_x + gidx);
        const bool v0 = (ox.x != 0.f) && !m0;
        const bool v1 = (ox.y != 0.f) && !m1;
        const bool v2 = (ox.z != 0.f) && !m2;
        const bool v3 = (ox.w != 0.f) && !m3;

        float l = (v0 ? l0 : 0.f) + (v1 ? l1 : 0.f) + (v2 ? l2 : 0.f) + (v3 ? l3 : 0.f);
        float c = (v0 ? 1.f : 0.f) + (v1 ? 1.f : 0.f) + (v2 ? 1.f : 0.f) + (v3 ? 1.f : 0.f);
        l = warp_red_sum(l);
        c = warp_red_sum(c);
        if (lane == 0) {
            atomicAdd(&ws[8 + b], l);
            atomicAdd(&ws[16 + b], c);
        }
    }
}

__global__ void finalize_kernel(const float* __restrict__ ws, float* __restrict__ out) {
    if (threadIdx.x == 0 && blockIdx.x == 0) {
        float acc = 0.f, nnz = 0.f, totc = 0.f;
#pragma unroll
        for (int i = 0; i < BB; ++i) {
            float c = ws[16 + i];
            totc += c;
            if (c > 0.f) { acc += ws[8 + i] / c; nnz += 1.f; }
        }
        out[0] = (totc > 0.f) ? acc / fmaxf(nnz, 1.f) : 0.f;
    }
}

extern "C" void kernel_launch(void* const* d_in, const int* in_sizes, int n_in,
                              void* d_out, int out_size, void* d_ws, size_t ws_size,
                              hipStream_t stream) {
    const float* s_feats = (const float*)d_in[0];
    const float* t_feats = (const float*)d_in[1];
    const float* center  = (const float*)d_in[2];
    const void*  mask    = d_in[3];
    const float* orig_x  = (const float*)d_in[4];
    float* ws = (float*)d_ws;

    detect_and_init<<<1, 256, 0, stream>>>((const uint4*)mask, ws);
    pixel_dino_main<<<NBLK, 512, 0, stream>>>(s_feats, t_feats, center, mask,
                                              orig_x, ws, ws);
    finalize_kernel<<<1, 64, 0, stream>>>(ws, (float*)d_out);
}

// Round 8
// 150.001 us; speedup vs baseline: 1.3016x; 1.3016x over previous
//
#include <hip/hip_runtime.h>
#include <math.h>

#define BB 8
#define DD 128
#define HWD 65536    // 256*256
#define NBLK 8192    // 524288 px / 64 px per block

__device__ __forceinline__ float warp_red_sum(float v) {
#pragma unroll
    for (int off = 32; off > 0; off >>= 1) v += __shfl_down(v, off, 64);
    return v;
}

// 512 threads = 8 waves. Block = 64 pixels x 128 channels. Wave owns 16
// channels, lane = pixel. The 32 per-thread floats live in NAMED scalars
// (no arrays -> no scratch demotion, no asm pins, generous VGPR budget ->
// no remat pressure). Pass 2 is register-only: features are read from HBM
// exactly once. LDS holds only 6.9 KB of reduce scratch.
__global__ __launch_bounds__(512, 2)
void pixel_dino_main(const float* __restrict__ s_feats,
                     const float* __restrict__ t_feats,
                     const float* __restrict__ center,
                     const void*  __restrict__ mask,
                     const float* __restrict__ orig_x,
                     float* __restrict__ ws) {
    const float TAU_S_INV = 10.0f, TAU_T_INV = 25.0f, EPSN = 1e-12f;
    const int tid  = threadIdx.x;
    const int lane = tid & 63;
    const int wave = tid >> 6;                      // 0..7
    const int b    = blockIdx.x >> 10;              // 1024 blocks per image
    const int pix0 = (blockIdx.x & 1023) << 6;
    const float* sp = s_feats + (size_t)b * (DD * HWD) + pix0 + lane;
    const float* tp = t_feats + (size_t)b * (DD * HWD) + pix0 + lane;
    const int D0 = wave << 4;

    // --- self-detect mask dtype from the first 1024 bytes (3 ballots) ---
    // flag: 0=uint8, 1=int32, 2=float32, 3=int64. All-zero window -> 0 (safe).
    const uint4 mw = ((const uint4*)mask)[lane];
    const unsigned int anyw = mw.x | mw.y | mw.z | mw.w;
    const unsigned long long nz  = __ballot(anyw != 0u);
    const unsigned long long gt1 = __ballot((anyw & 0xFEFEFEFEu) != 0u);  // byte>1 -> float bits
    const unsigned long long m4  = __ballot((anyw & 0xFFFFFF00u) != 0u);  // byte at off%4!=0 -> uint8
    const unsigned long long m84 = __ballot(((mw.y | mw.w) & 0xFFu) != 0u); // byte at off%8==4 -> int32
    const int flag = gt1 ? 2 : (m4 ? 0 : (m84 ? 1 : (nz ? 3 : 0)));

    // ---- single global read: 16 channels x {s, t-center} into named scalars ----
#define LD(i) \
    const float s##i = sp[(size_t)(D0 + i) * HWD]; \
    const float t##i = tp[(size_t)(D0 + i) * HWD] - center[D0 + i];
    LD(0)  LD(1)  LD(2)  LD(3)  LD(4)  LD(5)  LD(6)  LD(7)
    LD(8)  LD(9)  LD(10) LD(11) LD(12) LD(13) LD(14) LD(15)
#undef LD

    const float ss =
        (((s0*s0 + s1*s1) + (s2*s2 + s3*s3)) + ((s4*s4 + s5*s5) + (s6*s6 + s7*s7))) +
        (((s8*s8 + s9*s9) + (s10*s10 + s11*s11)) + ((s12*s12 + s13*s13) + (s14*s14 + s15*s15)));
    const float tt =
        (((t0*t0 + t1*t1) + (t2*t2 + t3*t3)) + ((t4*t4 + t5*t5) + (t6*t6 + t7*t7))) +
        (((t8*t8 + t9*t9) + (t10*t10 + t11*t11)) + ((t12*t12 + t13*t13) + (t14*t14 + t15*t15)));

    __shared__ float red[3][8][64];
    __shared__ float tot[3][64];
    red[0][wave][lane] = ss; red[1][wave][lane] = tt;
    __syncthreads();
    if (tid < 128) {                      // 2 quantities x 64 pixels
        const int q = tid >> 6, p = tid & 63;
        float v = 0.f;
#pragma unroll
        for (int w = 0; w < 8; ++w) v += red[q][w][p];
        tot[q][p] = v;
    }
    __syncthreads();
    const float rs = TAU_S_INV / fmaxf(sqrtf(tot[0][lane]), EPSN);
    const float rt = TAU_T_INV / fmaxf(sqrtf(tot[1][lane]), EPSN);

    // ---- pass 2: register-only exp sums.
    // No max-subtraction: |bv|<=10, |av|<=25 -> exp <= 7.2e10, fp32-safe. ----
    float eb = 0.f, ea = 0.f, eab = 0.f;
#define ACC(i) { \
    const float bv = s##i * rs; \
    const float e2 = __expf(t##i * rt); \
    eb += __expf(bv); ea += e2; eab = fmaf(e2, bv, eab); }
    ACC(0)  ACC(1)  ACC(2)  ACC(3)  ACC(4)  ACC(5)  ACC(6)  ACC(7)
    ACC(8)  ACC(9)  ACC(10) ACC(11) ACC(12) ACC(13) ACC(14) ACC(15)
#undef ACC

    red[0][wave][lane] = eb; red[1][wave][lane] = ea; red[2][wave][lane] = eab;
    __syncthreads();
    if (tid < 192) {                      // 3 quantities x 64 pixels
        const int q = tid >> 6, p = tid & 63;
        float v = 0.f;
#pragma unroll
        for (int w = 0; w < 8; ++w) v += red[q][w][p];
        tot[q][p] = v;
    }
    __syncthreads();

    if (wave == 0) {
        const float loss = __logf(tot[0][lane]) - tot[2][lane] / tot[1][lane];

        const int gidx = b * HWD + pix0 + lane;
        bool mval;
        if (flag == 0)      mval = ((const unsigned char*)mask)[gidx] != 0;
        else if (flag == 1) mval = ((const int*)mask)[gidx] != 0;
        else if (flag == 2) mval = ((const float*)mask)[gidx] != 0.f;
        else                mval = ((const long long*)mask)[gidx] != 0;
        const bool valid = (orig_x[gidx] != 0.f) && !mval;

        float l = valid ? loss : 0.f;
        float c = valid ? 1.f  : 0.f;
        l = warp_red_sum(l);
        c = warp_red_sum(c);
        if (lane == 0) {
            atomicAdd(&ws[8 + b], l);
            atomicAdd(&ws[16 + b], c);
        }
    }
}

__global__ void finalize_kernel(const float* __restrict__ ws, float* __restrict__ out) {
    if (threadIdx.x == 0 && blockIdx.x == 0) {
        float acc = 0.f, nnz = 0.f, totc = 0.f;
#pragma unroll
        for (int i = 0; i < BB; ++i) {
            float c = ws[16 + i];
            totc += c;
            if (c > 0.f) { acc += ws[8 + i] / c; nnz += 1.f; }
        }
        out[0] = (totc > 0.f) ? acc / fmaxf(nnz, 1.f) : 0.f;
    }
}

extern "C" void kernel_launch(void* const* d_in, const int* in_sizes, int n_in,
                              void* d_out, int out_size, void* d_ws, size_t ws_size,
                              hipStream_t stream) {
    const float* s_feats = (const float*)d_in[0];
    const float* t_feats = (const float*)d_in[1];
    const float* center  = (const float*)d_in[2];
    const void*  mask    = d_in[3];
    const float* orig_x  = (const float*)d_in[4];
    float* ws = (float*)d_ws;

    hipMemsetAsync(d_ws, 0, 128, stream);
    pixel_dino_main<<<NBLK, 512, 0, stream>>>(s_feats, t_feats, center, mask,
                                              orig_x, ws);
    finalize_kernel<<<1, 64, 0, stream>>>(ws, (float*)d_out);
}